// Round 2
// 524.837 us; speedup vs baseline: 1.0497x; 1.0497x over previous
//
#include <hip/hip_runtime.h>
#include <math.h>

// ContinuousFilterConv, round 7: R6 (persistent pipelined MLP) hardened.
// R6 bench died with "container failed twice" (no counters) -- infra or
// kernel-induced failure, indistinguishable. R7 keeps the architecture but:
//  - restores barrier (c) after the flush so correctness no longer relies
//    on the wave-locality argument for the flush/h1-write overlap;
//  - issues the atom gather between GEMM1 and GEMM2 (16 fewer live VGPRs
//    across GEMM1; latency still hidden under GEMM2).
// Architecture (from R6):
//  - 768 persistent blocks grid-stride 12500 tiles; W frags staged to LDS
//    once per block (was: once per 64 edges in R5).
//  - Edge A-fragments loaded global->register directly (lane(q,n) of wave w
//    reads edge w*16+n chunks [q*8,+8) and [32+q*8,+8)); A1 LDS stage gone.
//  - h1 transpose wave-local (4 KB slice + lgkmcnt(0)).
//  - Next-tile perm/edge_list/edge-row prefetch hides global latency.
// Numerics identical to R5 (same split-bf16 3-term MFMA order, same
// tanh/exp, same swizzle, same interior-store/boundary-atomic flush).

#define TE 64
#define HID 64
#define NBLK_MLP 768

typedef __attribute__((ext_vector_type(8))) short short8;
typedef __attribute__((ext_vector_type(4))) float float4v;

__device__ __forceinline__ float fast_tanh(float x) {
    float t = __expf(2.0f * x);
    return 1.0f - 2.0f * __builtin_amdgcn_rcpf(t + 1.0f);
}

__device__ __forceinline__ void split_bf16(float x, unsigned short& hi,
                                           unsigned short& lo) {
    unsigned b = __float_as_uint(x);
    hi = (unsigned short)(b >> 16);
    float hf = __uint_as_float(b & 0xffff0000u);
    lo = (unsigned short)(__float_as_uint(x - hf) >> 16);
}

__device__ __forceinline__ void split8(const float4 u0, const float4 u1,
                                       short8& h, short8& l) {
    float xv[8] = {u0.x, u0.y, u0.z, u0.w, u1.x, u1.y, u1.z, u1.w};
    #pragma unroll
    for (int j = 0; j < 8; ++j) {
        unsigned short hi, lo;
        split_bf16(xv[j], hi, lo);
        h[j] = (short)hi; l[j] = (short)lo;
    }
}

// ---------------- W pre-split into MFMA B-fragment order ----------------
// B frag for 16x16x32: lane(q,n) holds B[k=ks*32+q*8+j][f=nt*16+n], j=0..7.
// Linear: chunk = (nt*2+ks)*64 + q*16 + n, elem = chunk*8 + j.
// wpack: [W1h 4096][W1l 4096][W2h 4096][W2l 4096] u16.
__global__ __launch_bounds__(256) void pack_w(
    const float* __restrict__ W1, const float* __restrict__ W2,
    unsigned short* __restrict__ wpack)
{
    int t = threadIdx.x;
    for (int i = 0; i < 16; ++i) {
        int idx = t * 16 + i;              // 0..4095
        int k = idx >> 6, f = idx & 63;
        int nt = f >> 4, n = f & 15, ks = k >> 5, q = (k >> 3) & 3, j = k & 7;
        int fi = (((nt * 2 + ks) * 4 + q) * 16 + n) * 8 + j;
        unsigned short hi, lo;
        split_bf16(W1[idx], hi, lo);
        wpack[fi] = hi; wpack[4096 + fi] = lo;
        split_bf16(W2[idx], hi, lo);
        wpack[8192 + fi] = hi; wpack[12288 + fi] = lo;
    }
}

// ---------------- sort pipeline (unchanged) ----------------

__global__ __launch_bounds__(256) void hist_kernel(
    const int2* __restrict__ edge_list, int* __restrict__ cursor, int E)
{
    int i = blockIdx.x * blockDim.x + threadIdx.x;
    if (i < E) atomicAdd(&cursor[edge_list[i].x], 1);
}

__global__ __launch_bounds__(1024) void scanA_kernel(
    int* __restrict__ a, int* __restrict__ blocksums, int N)
{
    __shared__ int wsum[16];
    const int t = threadIdx.x;
    const int lane = t & 63, wv = t >> 6;
    int i = blockIdx.x * 1024 + t;
    int x = (i < N) ? a[i] : 0;
    int v = x;
    #pragma unroll
    for (int d = 1; d < 64; d <<= 1) {
        int y = __shfl_up(v, d);
        if (lane >= d) v += y;
    }
    if (lane == 63) wsum[wv] = v;
    __syncthreads();
    if (wv == 0 && lane < 16) {
        int s = wsum[lane];
        #pragma unroll
        for (int d = 1; d < 16; d <<= 1) {
            int y = __shfl_up(s, d);
            if (lane >= d) s += y;
        }
        wsum[lane] = s;
    }
    __syncthreads();
    int incl = v + ((wv == 0) ? 0 : wsum[wv - 1]);
    if (i < N) a[i] = incl - x;
    if (t == 1023) blocksums[blockIdx.x] = incl;
}

__global__ __launch_bounds__(64) void scanB_kernel(int* __restrict__ bs, int nb)
{
    int lane = threadIdx.x;
    int x = (lane < nb) ? bs[lane] : 0;
    int v = x;
    #pragma unroll
    for (int d = 1; d < 64; d <<= 1) {
        int y = __shfl_up(v, d);
        if (lane >= d) v += y;
    }
    if (lane < nb) bs[lane] = v - x;
}

__global__ __launch_bounds__(1024) void scanC_kernel(
    int* __restrict__ a, const int* __restrict__ blocksums, int N)
{
    int i = blockIdx.x * 1024 + threadIdx.x;
    if (i < N) a[i] += blocksums[blockIdx.x];
}

__global__ __launch_bounds__(256) void perm_kernel(
    const int2* __restrict__ edge_list, int* __restrict__ cursor,
    int* __restrict__ perm, int E)
{
    int i = blockIdx.x * blockDim.x + threadIdx.x;
    if (i < E) {
        int d = edge_list[i].x;
        int p = atomicAdd(&cursor[d], 1);
        perm[p] = i;
    }
}

// ---------------- persistent fused MFMA MLP + segment scatter ----------------
// LDS map (48 KB):
//   [0,16K)  : B1 frags (W1 hi/lo)   -- persistent, never overwritten
//   [16,32K) : B2 frags (W2 hi/lo)   -- persistent
//   [32,48K) : h1 slices (4 KB/wave) aliased with ACC (64 seg x 64 f32)
// Per-tile barriers: (a) pre-LDS-atomics, (b) pre-flush, (c) post-flush.

__global__ __launch_bounds__(256, 3) void edge_mlp_sorted(
    const float* __restrict__ atom,
    const float* __restrict__ edge_emb,
    const unsigned short* __restrict__ wpack,
    const float* __restrict__ b1,
    const float* __restrict__ b2,
    const float* __restrict__ coef,
    const int*   __restrict__ edge_list,       // [E,2]: [dest, src]
    const int*   __restrict__ perm,
    float* __restrict__ num,
    float* __restrict__ den,
    int E)
{
    __shared__ __align__(16) unsigned char SH[49152];
    __shared__ float denacc[TE];
    __shared__ int   segdest[TE];

    unsigned short* B1 = (unsigned short*)SH;            // W1 hi/lo frags
    unsigned short* B2 = (unsigned short*)(SH + 16384);  // W2 hi/lo frags
    float* H1  = (float*)(SH + 32768);                   // h1 slices / ACC
    float* ACC = H1;

    const int t    = threadIdx.x;
    const int w    = t >> 6;
    const int lane = t & 63;
    const int q    = lane >> 4;
    const int n    = lane & 15;
    const int ntiles = (E + TE - 1) / TE;
    const int stride = gridDim.x;

    // ---- one-time: W frags global->LDS, biases->regs, zero ACC/denacc ----
    {
        const uint4* wp = (const uint4*)wpack;
        uint4* shw = (uint4*)SH;
        #pragma unroll
        for (int i = 0; i < 8; ++i)
            shw[t + 256 * i] = wp[t + 256 * i];          // 32 KB
    }
    float b1v[4], b2v[4], cfv[4];
    #pragma unroll
    for (int nt = 0; nt < 4; ++nt) {
        b1v[nt] = b1[nt * 16 + n];
        b2v[nt] = b2[nt * 16 + n];
        cfv[nt] = coef[nt * 16 + n];
    }
    {
        float4 z4 = {0.f, 0.f, 0.f, 0.f};
        float4* az = (float4*)ACC;
        #pragma unroll
        for (int i = 0; i < 4; ++i) az[t + 256 * i] = z4;
        if (t < TE) denacc[t] = 0.f;
    }
    __syncthreads();

    // ---- pipeline prime ----
    int tt = blockIdx.x;
    int p_cur = 0, p_nxt = 0, p_nxt2 = 0;
    int2 ds_cur = make_int2(0, 0), ds_nxt = make_int2(0, 0);
    float4 rA0, rA1, rA2, rA3;
    float4 rN0 = {0,0,0,0}, rN1 = {0,0,0,0}, rN2 = {0,0,0,0}, rN3 = {0,0,0,0};
    {
        int eg = tt * TE + lane; if (eg >= E) eg = E - 1;
        p_cur = perm[eg];
        ds_cur = ((const int2*)edge_list)[p_cur];
        int pid = __shfl(p_cur, w * 16 + n);
        const float* ep = edge_emb + (size_t)pid * HID;
        rA0 = *(const float4*)(ep + q * 8);
        rA1 = *(const float4*)(ep + q * 8 + 4);
        rA2 = *(const float4*)(ep + 32 + q * 8);
        rA3 = *(const float4*)(ep + 36 + q * 8);
        int t2 = tt + stride;
        if (t2 < ntiles) {
            int eg2 = t2 * TE + lane; if (eg2 >= E) eg2 = E - 1;
            p_nxt = perm[eg2];
        }
    }

    for (; tt < ntiles; tt += stride) {
        const int eb = tt * TE;
        const bool hn = (tt + stride) < ntiles;

        // ---- seg scan (per-wave redundant; lane <-> tile edge) ----
        int d = ds_cur.x, s = ds_cur.y;
        int dprev = __shfl_up(d, 1);
        int head = (lane == 0 || dprev != d) ? 1 : 0;
        int sv = head;
        #pragma unroll
        for (int m = 1; m < 64; m <<= 1) {
            int y = __shfl_up(sv, m);
            if (lane >= m) sv += y;
        }
        int sidx = sv - 1;
        int nseg = __shfl(sv, 63);

        // prev/next tile boundary dests (lanes 0/63; broadcast at flush)
        int pdnd = -1;
        if (lane == 0 && eb > 0)        pdnd = edge_list[2 * perm[eb - 1]];
        if (lane == 63 && eb + TE < E)  pdnd = edge_list[2 * perm[eb + TE]];

        // own-edge seg ids + src indices (gather issued after GEMM1)
        int seg_r[4], src_r[4];
        #pragma unroll
        for (int r = 0; r < 4; ++r) {
            int el = w * 16 + q * 4 + r;
            seg_r[r] = __shfl(sidx, el);
            src_r[r] = __shfl(s, el);
        }

        // ---- prefetch next tile (overlaps both GEMMs) ----
        if (hn) {
            ds_nxt = ((const int2*)edge_list)[p_nxt];
            int pid2 = __shfl(p_nxt, w * 16 + n);
            const float* ep2 = edge_emb + (size_t)pid2 * HID;
            rN0 = *(const float4*)(ep2 + q * 8);
            rN1 = *(const float4*)(ep2 + q * 8 + 4);
            rN2 = *(const float4*)(ep2 + 32 + q * 8);
            rN3 = *(const float4*)(ep2 + 36 + q * 8);
            int t3 = tt + 2 * stride;
            if (t3 < ntiles) {
                int eg3 = t3 * TE + lane; if (eg3 >= E) eg3 = E - 1;
                p_nxt2 = perm[eg3];
            }
        }

        // ---- GEMM1: h1 = tanh(E @ W1 + b1), split-bf16 ----
        short8 a1h[2], a1l[2];
        split8(rA0, rA1, a1h[0], a1l[0]);
        split8(rA2, rA3, a1h[1], a1l[1]);
        float4v c1[4];
        #pragma unroll
        for (int i = 0; i < 4; ++i) c1[i] = (float4v){0.f, 0.f, 0.f, 0.f};
        #pragma unroll
        for (int nt = 0; nt < 4; ++nt) {
            #pragma unroll
            for (int ks = 0; ks < 2; ++ks) {
                int cb = (nt * 2 + ks) * 64 + lane;
                short8 bh = *(const short8*)&B1[cb * 8];
                short8 bl = *(const short8*)&B1[4096 + cb * 8];
                c1[nt] = __builtin_amdgcn_mfma_f32_16x16x32_bf16(a1h[ks], bh, c1[nt], 0, 0, 0);
                c1[nt] = __builtin_amdgcn_mfma_f32_16x16x32_bf16(a1h[ks], bl, c1[nt], 0, 0, 0);
                c1[nt] = __builtin_amdgcn_mfma_f32_16x16x32_bf16(a1l[ks], bh, c1[nt], 0, 0, 0);
            }
        }

        // ---- atom gather issue (latency hides under transpose + GEMM2) ----
        float av[4][4];
        #pragma unroll
        for (int r = 0; r < 4; ++r) {
            const float* ap = atom + (size_t)src_r[r] * HID + n;
            #pragma unroll
            for (int nt = 0; nt < 4; ++nt) av[r][nt] = ap[nt * 16];
        }

        // ---- tanh + h1 write (wave-local slice, swizzled) ----
        float* h1w = H1 + w * 1024;
        #pragma unroll
        for (int nt = 0; nt < 4; ++nt) {
            int f = nt * 16 + n;
            #pragma unroll
            for (int r = 0; r < 4; ++r) {
                int m = q * 4 + r;
                h1w[m * 64 + (f ^ ((m & 7) << 3))] = fast_tanh(c1[nt][r] + b1v[nt]);
            }
        }
        // wave-local fence: writes above are consumed by this wave only
        asm volatile("s_waitcnt lgkmcnt(0)" ::: "memory");

        // ---- read back as GEMM2 A frags, split to bf16 ----
        short8 a2h[2], a2l[2];
        {
            int m = n;
            #pragma unroll
            for (int ks2 = 0; ks2 < 2; ++ks2) {
                int F0 = (ks2 * 32 + q * 8) ^ ((m & 7) << 3);
                const float* sp = h1w + m * 64 + F0;
                float4 u0 = *(const float4*)&sp[0];
                float4 u1 = *(const float4*)&sp[4];
                split8(u0, u1, a2h[ks2], a2l[ks2]);
            }
        }
        // ---- zero own slice (becomes ACC rows w*16..w*16+15) ----
        {
            float4 z4 = {0.f, 0.f, 0.f, 0.f};
            float* zp = h1w + lane * 16;
            #pragma unroll
            for (int i = 0; i < 4; ++i) *(float4*)(zp + 4 * i) = z4;
        }

        // ---- GEMM2: h2 = h1 @ W2 + b2 ----
        float4v c2[4];
        #pragma unroll
        for (int i = 0; i < 4; ++i) c2[i] = (float4v){0.f, 0.f, 0.f, 0.f};
        #pragma unroll
        for (int nt = 0; nt < 4; ++nt) {
            #pragma unroll
            for (int ks = 0; ks < 2; ++ks) {
                int cb = (nt * 2 + ks) * 64 + lane;
                short8 bh = *(const short8*)&B2[cb * 8];
                short8 bl = *(const short8*)&B2[4096 + cb * 8];
                c2[nt] = __builtin_amdgcn_mfma_f32_16x16x32_bf16(a2h[ks], bh, c2[nt], 0, 0, 0);
                c2[nt] = __builtin_amdgcn_mfma_f32_16x16x32_bf16(a2h[ks], bl, c2[nt], 0, 0, 0);
                c2[nt] = __builtin_amdgcn_mfma_f32_16x16x32_bf16(a2l[ks], bh, c2[nt], 0, 0, 0);
            }
        }

        // ---- msg, attention ----
        float msg[4][4], partial[4], at[4];
        #pragma unroll
        for (int r = 0; r < 4; ++r) {
            float p = 0.f;
            #pragma unroll
            for (int nt = 0; nt < 4; ++nt) {
                float hv = c2[nt][r] + b2v[nt];
                msg[r][nt] = av[r][nt] * hv;
                p = fmaf(msg[r][nt], cfv[nt], p);
            }
            partial[r] = p;
        }
        #pragma unroll
        for (int m = 1; m < 16; m <<= 1) {
            #pragma unroll
            for (int r = 0; r < 4; ++r)
                partial[r] += __shfl_xor(partial[r], m);
        }
        #pragma unroll
        for (int r = 0; r < 4; ++r) {
            int eg = eb + w * 16 + q * 4 + r;
            at[r] = (eg < E) ? __expf(partial[r]) : 0.f;
        }

        __syncthreads();   // (a) all slice-zeros visible

        // segdest written between (a) and (b): safe vs prev tile's flush
        if (head) segdest[sidx] = d;

        // ---- register run-combine over 4 consecutive sorted edges ----
        {
            int curseg = seg_r[0];
            float acc0 = msg[0][0] * at[0], acc1 = msg[0][1] * at[0];
            float acc2 = msg[0][2] * at[0], acc3 = msg[0][3] * at[0];
            float rd = at[0];
            #pragma unroll
            for (int r = 1; r < 4; ++r) {
                if (seg_r[r] == curseg) {
                    acc0 = fmaf(msg[r][0], at[r], acc0);
                    acc1 = fmaf(msg[r][1], at[r], acc1);
                    acc2 = fmaf(msg[r][2], at[r], acc2);
                    acc3 = fmaf(msg[r][3], at[r], acc3);
                    rd += at[r];
                } else {
                    float* p = &ACC[curseg * 64 + n];
                    atomicAdd(p + 0,  acc0); atomicAdd(p + 16, acc1);
                    atomicAdd(p + 32, acc2); atomicAdd(p + 48, acc3);
                    if (n == 0) atomicAdd(&denacc[curseg], rd);
                    curseg = seg_r[r];
                    acc0 = msg[r][0] * at[r]; acc1 = msg[r][1] * at[r];
                    acc2 = msg[r][2] * at[r]; acc3 = msg[r][3] * at[r];
                    rd = at[r];
                }
            }
            float* p = &ACC[curseg * 64 + n];
            atomicAdd(p + 0,  acc0); atomicAdd(p + 16, acc1);
            atomicAdd(p + 32, acc2); atomicAdd(p + 48, acc3);
            if (n == 0) atomicAdd(&denacc[curseg], rd);
        }
        __syncthreads();   // (b) atomics done

        // ---- flush: interior = stores, boundary = atomics ----
        {
            int prevd = __shfl(pdnd, 0);
            int nextd = __shfl(pdnd, 63);
            int sg = t >> 2;
            int qq = t & 3;
            if (sg < nseg) {
                int d2 = segdest[sg];
                bool bnd = (sg == 0 && d2 == prevd) ||
                           (sg == nseg - 1 && d2 == nextd);
                float* np = num + (size_t)d2 * HID + qq * 16;
                const float* sp = &ACC[sg * 64 + qq * 16];
                if (bnd) {
                    #pragma unroll
                    for (int j = 0; j < 16; ++j) atomicAdd(np + j, sp[j]);
                    if (qq == 0) { atomicAdd(&den[d2], denacc[sg]); denacc[sg] = 0.f; }
                } else {
                    #pragma unroll
                    for (int j = 0; j < 4; ++j)
                        ((float4*)np)[j] = *(const float4*)(sp + 4 * j);
                    if (qq == 0) { den[d2] = denacc[sg]; denacc[sg] = 0.f; }
                }
            }
        }
        __syncthreads();   // (c) flush reads done before next tile's h1 write

        if (hn) {
            ds_cur = ds_nxt;
            rA0 = rN0; rA1 = rN1; rA2 = rN2; rA3 = rN3;
            p_nxt = p_nxt2;
        }
    }
}

__global__ __launch_bounds__(256) void finalize_kernel(
    float* __restrict__ out, const float* __restrict__ den, int n16)
{
    int i = blockIdx.x * blockDim.x + threadIdx.x;
    if (i >= n16) return;
    float d = den[i >> 4];
    if (d > 0.f) {
        float4* p = (float4*)out + i;
        float4 v = *p;
        float r = 1.0f / d;
        v.x *= r; v.y *= r; v.z *= r; v.w *= r;
        *p = v;
    }
}

extern "C" void kernel_launch(void* const* d_in, const int* in_sizes, int n_in,
                              void* d_out, int out_size, void* d_ws, size_t ws_size,
                              hipStream_t stream) {
    const float* atom      = (const float*)d_in[0];
    const float* edge_emb  = (const float*)d_in[1];
    const float* W1        = (const float*)d_in[2];
    const float* b1        = (const float*)d_in[3];
    const float* W2        = (const float*)d_in[4];
    const float* b2        = (const float*)d_in[5];
    const float* coef      = (const float*)d_in[6];
    const int*   edge_list = (const int*)d_in[7];

    const int N = in_sizes[0] / HID;   // 50000
    const int E = in_sizes[1] / HID;   // 800000

    // ws: [den N f32][cursor N i32][blocksums 64][perm E i32][wpack 16384 u16]
    float* den       = (float*)d_ws;
    int*   cursor    = (int*)d_ws + N;
    int*   blocksums = (int*)d_ws + 2 * N;
    int*   perm      = (int*)d_ws + 2 * N + 64;
    unsigned short* wpack = (unsigned short*)((int*)d_ws + 2 * N + 64 + E);

    hipMemsetAsync(d_out, 0, (size_t)N * HID * sizeof(float), stream);
    hipMemsetAsync(d_ws, 0, (size_t)(2 * N) * sizeof(int), stream);

    pack_w<<<1, 256, 0, stream>>>(W1, W2, wpack);

    int eblk = (E + 255) / 256;
    int nb   = (N + 1023) / 1024;
    hist_kernel<<<eblk, 256, 0, stream>>>((const int2*)edge_list, cursor, E);
    scanA_kernel<<<nb, 1024, 0, stream>>>(cursor, blocksums, N);
    scanB_kernel<<<1, 64, 0, stream>>>(blocksums, nb);
    scanC_kernel<<<nb, 1024, 0, stream>>>(cursor, blocksums, N);
    perm_kernel<<<eblk, 256, 0, stream>>>((const int2*)edge_list, cursor, perm, E);

    int ntl  = (E + TE - 1) / TE;
    int nblk = ntl < NBLK_MLP ? ntl : NBLK_MLP;
    edge_mlp_sorted<<<nblk, 256, 0, stream>>>(
        atom, edge_emb, wpack, b1, b2, coef, edge_list, perm,
        (float*)d_out, den, E);

    int n16 = N * (HID / 4);
    finalize_kernel<<<(n16 + 255) / 256, 256, 0, stream>>>((float*)d_out, den, n16);
}